// Round 1
// baseline (224.302 us; speedup 1.0000x reference)
//
#include <hip/hip_runtime.h>
#include <hip/hip_bf16.h>
#include <cstdint>

static constexpr int   Nb = 2;
static constexpr int   L  = 4800;
static constexpr int   S  = 4800;
static constexpr int   C  = 256;
static constexpr float THR = 0.2f;
static constexpr float SIM_SCALE = 1.0f / 25.6f; // 1/(C*TEMP), folds both 1/sqrt(C)

using f32x4  = __attribute__((ext_vector_type(4))) float;
using bf16x8 = __attribute__((ext_vector_type(8))) short;
using u32x4  = __attribute__((ext_vector_type(4))) unsigned int;

// ---------------- fp32 -> bf16 (RNE) conversion ----------------
__device__ inline unsigned short bf16_rne(float x) {
    unsigned u = __float_as_uint(x);
    unsigned r = (u + 0x7FFFu + ((u >> 16) & 1u)) >> 16;
    return (unsigned short)r;
}

__global__ __launch_bounds__(256) void cvt_bf16(const float* __restrict__ in,
                                                unsigned short* __restrict__ out, int n8) {
    int i = blockIdx.x * 256 + threadIdx.x;
    if (i >= n8) return;
    f32x4 a = *(const f32x4*)(in + (size_t)i * 8);
    f32x4 b = *(const f32x4*)(in + (size_t)i * 8 + 4);
    union { unsigned short us[8]; u32x4 v; } r;
#pragma unroll
    for (int j = 0; j < 4; j++) r.us[j] = bf16_rne(a[j]);
#pragma unroll
    for (int j = 0; j < 4; j++) r.us[4 + j] = bf16_rne(b[j]);
    *(u32x4*)(out + (size_t)i * 8) = r.v;
}

// ---------------- GEMM: sim = A·B^T / 25.6, + exp-sum stats ----------------
// Tile 96x96, 4 waves (2x2), each wave 48x48 = 3x3 frags of 16x16x32 MFMA.
#define BM 96
#define BK 64

__global__ __launch_bounds__(256) void gemm_stats(
    const unsigned short* __restrict__ Abf,  // [N,L,C] bf16
    const unsigned short* __restrict__ Bbf,  // [N,S,C] bf16
    float* __restrict__ sim_out,             // [N,L,S] (conf region of d_out)
    float* __restrict__ rowSum,              // [N,L]  D2 = sum_s exp(sim)
    float* __restrict__ colSum)              // [N,S]  D1 = sum_l exp(sim)
{
    __shared__ unsigned short As[BM * BK];
    __shared__ unsigned short Bs[BM * BK];

    const int n  = blockIdx.z;
    const int rb = blockIdx.y * BM;
    const int cb = blockIdx.x * BM;
    const int t  = threadIdx.x;
    const int lane = t & 63;
    const int wid  = t >> 6;
    const int wr = wid >> 1, wc = wid & 1;

    const unsigned short* Ag = Abf + ((size_t)n * L + rb) * C;
    const unsigned short* Bg = Bbf + ((size_t)n * S + cb) * C;

    f32x4 acc[3][3] = {};

    for (int kt = 0; kt < C; kt += BK) {
        // stage 96x64 bf16 tiles of A and B (768 16B chunks each; 3 per thread)
#pragma unroll
        for (int i = 0; i < 3; i++) {
            int cch   = t + i * 256;      // 0..767
            int row   = cch >> 3;         // 0..95
            int col16 = cch & 7;          // 16B chunk in row
            u32x4 av = *(const u32x4*)(Ag + (size_t)row * C + kt + col16 * 8);
            u32x4 bv = *(const u32x4*)(Bg + (size_t)row * C + kt + col16 * 8);
            int off = row * 64 + ((col16 * 8) ^ ((row & 7) << 3)); // XOR swizzle (16B units)
            *(u32x4*)&As[off] = av;
            *(u32x4*)&Bs[off] = bv;
        }
        __syncthreads();

#pragma unroll
        for (int kk = 0; kk < 2; kk++) {
            bf16x8 a[3], b[3];
            const int kElem = kk * 32 + (lane >> 4) * 8;
#pragma unroll
            for (int f = 0; f < 3; f++) {
                int ra = wr * 48 + f * 16 + (lane & 15);
                a[f] = *(const bf16x8*)&As[ra * 64 + (kElem ^ ((ra & 7) << 3))];
                int rbi = wc * 48 + f * 16 + (lane & 15);
                b[f] = *(const bf16x8*)&Bs[rbi * 64 + (kElem ^ ((rbi & 7) << 3))];
            }
#pragma unroll
            for (int fi = 0; fi < 3; fi++)
#pragma unroll
                for (int fj = 0; fj < 3; fj++)
                    acc[fi][fj] = __builtin_amdgcn_mfma_f32_16x16x32_bf16(
                        a[fi], b[fj], acc[fi][fj], 0, 0, 0);
        }
        __syncthreads();
    }

    // epilogue: write sim, accumulate exp-sums
    const int rowBase = rb + wr * 48;
    const int colBase = cb + wc * 48;
    float cpart[3] = {0.f, 0.f, 0.f};

#pragma unroll
    for (int fi = 0; fi < 3; fi++) {
        f32x4 rpart = {0.f, 0.f, 0.f, 0.f};
        const int rsub = fi * 16 + (lane >> 4) * 4;
#pragma unroll
        for (int fj = 0; fj < 3; fj++) {
            const int col = colBase + fj * 16 + (lane & 15);
            float* outp = sim_out + ((size_t)n * L + rowBase + rsub) * S + col;
#pragma unroll
            for (int r = 0; r < 4; r++) {
                float simv = acc[fi][fj][r] * SIM_SCALE;
                outp[(size_t)r * S] = simv;
                float e = expf(simv);
                rpart[r] += e;
                cpart[fj] += e;
            }
        }
#pragma unroll
        for (int r = 0; r < 4; r++) {
            float v = rpart[r];
            v += __shfl_xor(v, 1);
            v += __shfl_xor(v, 2);
            v += __shfl_xor(v, 4);
            v += __shfl_xor(v, 8);
            if ((lane & 15) == 0)
                atomicAdd(&rowSum[(size_t)n * L + rowBase + rsub + r], v);
        }
    }
#pragma unroll
    for (int fj = 0; fj < 3; fj++) {
        float v = cpart[fj];
        v += __shfl_xor(v, 16);
        v += __shfl_xor(v, 32);
        if (lane < 16)
            atomicAdd(&colSum[(size_t)n * S + colBase + fj * 16 + lane], v);
    }
}

// ---------------- conf = exp(2*sim)/(D1[s]*D2[l]) in-place, + row/col max ----------------
__global__ __launch_bounds__(256) void conf_pass(
    float* __restrict__ conf,             // in: sim, out: conf  [N,L,S]
    const float* __restrict__ rowSum,     // [N,L]
    const float* __restrict__ colSum,     // [N,S]
    unsigned int* __restrict__ rowMax,    // [N,L] float bits
    unsigned int* __restrict__ colMax)    // [N,S] float bits
{
    const int ROWS = 32;
    const int CBLK = 19;                  // ceil(4800/256)
    const int tilesPerN = (L / ROWS) * CBLK; // 150*19
    const int wid = threadIdx.x >> 6, lane = threadIdx.x & 63;
    const int tw = blockIdx.x * 4 + wid;
    if (tw >= Nb * tilesPerN) return;
    const int n   = tw / tilesPerN;
    const int rem = tw % tilesPerN;
    const int r0  = (rem / CBLK) * ROWS;
    const int c   = (rem % CBLK) * 256 + lane * 4;
    const bool act = (c < S);

    f32x4 invD1 = {0.f, 0.f, 0.f, 0.f};
    if (act) {
        f32x4 d1 = *(const f32x4*)&colSum[(size_t)n * S + c];
#pragma unroll
        for (int j = 0; j < 4; j++) invD1[j] = 1.0f / d1[j];
    }
    f32x4 cmax = {0.f, 0.f, 0.f, 0.f};

    for (int r = r0; r < r0 + ROWS; r++) {
        float invD2 = 1.0f / rowSum[(size_t)n * L + r];
        float rmax = 0.f;
        if (act) {
            float* p = conf + ((size_t)n * L + r) * S + c;
            f32x4 sv = *(const f32x4*)p;
            f32x4 cv;
#pragma unroll
            for (int j = 0; j < 4; j++) {
                float e2 = expf(2.0f * sv[j]);
                cv[j] = e2 * invD1[j] * invD2;
                cmax[j] = fmaxf(cmax[j], cv[j]);
                rmax = fmaxf(rmax, cv[j]);
            }
            *(f32x4*)p = cv;
        }
#pragma unroll
        for (int d = 1; d < 64; d <<= 1) rmax = fmaxf(rmax, __shfl_xor(rmax, d));
        if (lane == 0)
            atomicMax(&rowMax[(size_t)n * L + r], __float_as_uint(rmax));
    }
    if (act) {
#pragma unroll
        for (int j = 0; j < 4; j++)
            atomicMax(&colMax[(size_t)n * S + c + j], __float_as_uint(cmax[j]));
    }
}

// ---------------- mask ----------------
__device__ inline bool border_ok(int idx) {
    int h = idx / 80, w = idx % 80;
    return (h >= 2) & (h < 58) & (w >= 2) & (w < 78);
}

__global__ __launch_bounds__(256) void mask_pass(
    const float* __restrict__ conf,
    const unsigned int* __restrict__ rowMax,
    const unsigned int* __restrict__ colMax,
    float* __restrict__ mask)
{
    const size_t total4 = (size_t)Nb * L * S / 4;
    const size_t stride = (size_t)gridDim.x * blockDim.x;
    for (size_t i = (size_t)blockIdx.x * blockDim.x + threadIdx.x; i < total4; i += stride) {
        size_t row = i / (S / 4);          // n*L + l
        int c4 = (int)(i % (S / 4));
        int n = (int)(row / L);
        int l = (int)(row % L);
        int s0 = c4 * 4;
        f32x4 cv = *(const f32x4*)&conf[i * 4];
        unsigned rm = rowMax[row];
        u32x4 cm = *(const u32x4*)&colMax[(size_t)n * S + s0];
        bool vL = border_ok(l);
        f32x4 mv;
#pragma unroll
        for (int j = 0; j < 4; j++) {
            unsigned cb = __float_as_uint(cv[j]);
            bool m = (cv[j] > THR) && vL && border_ok(s0 + j) && (cb == rm) && (cb == cm[j]);
            mv[j] = m ? 1.0f : 0.0f;
        }
        *(f32x4*)&mask[i * 4] = mv;
    }
}

// ---------------- launch ----------------
extern "C" void kernel_launch(void* const* d_in, const int* in_sizes, int n_in,
                              void* d_out, int out_size, void* d_ws, size_t ws_size,
                              hipStream_t stream) {
    (void)in_sizes; (void)n_in; (void)out_size; (void)ws_size;
    const float* f0 = (const float*)d_in[0];
    const float* f1 = (const float*)d_in[1];

    float* conf = (float*)d_out;                       // N*L*S
    float* mask = conf + (size_t)Nb * L * S;

    unsigned short* Abf = (unsigned short*)d_ws;       // N*L*C bf16
    unsigned short* Bbf = Abf + (size_t)Nb * L * C;
    float* rowSum = (float*)(Bbf + (size_t)Nb * S * C);
    float* colSum = rowSum + (size_t)Nb * L;
    unsigned int* rowMax = (unsigned int*)(colSum + (size_t)Nb * S);
    unsigned int* colMax = rowMax + (size_t)Nb * L;

    // zero the 4 contiguous stat arrays (2*(N*L + N*S) floats/uints)
    hipMemsetAsync(rowSum, 0, (size_t)2 * (Nb * L + Nb * S) * 4, stream);

    const int n8 = Nb * L * C / 8;
    cvt_bf16<<<(n8 + 255) / 256, 256, 0, stream>>>(f0, Abf, n8);
    cvt_bf16<<<(n8 + 255) / 256, 256, 0, stream>>>(f1, Bbf, n8);

    gemm_stats<<<dim3(S / BM, L / BM, Nb), 256, 0, stream>>>(Abf, Bbf, conf, rowSum, colSum);

    const int nTiles = Nb * (L / 32) * 19;
    conf_pass<<<(nTiles + 3) / 4, 256, 0, stream>>>(conf, rowSum, colSum, rowMax, colMax);

    mask_pass<<<4096, 256, 0, stream>>>(conf, rowMax, colMax, mask);
}

// Round 2
// 206.218 us; speedup vs baseline: 1.0877x; 1.0877x over previous
//
#include <hip/hip_runtime.h>
#include <hip/hip_bf16.h>
#include <cstdint>

static constexpr int   Nb = 2;
static constexpr int   L  = 4800;
static constexpr int   S  = 4800;
static constexpr int   C  = 256;
static constexpr float THR = 0.2f;
static constexpr float SIM_SCALE = 1.0f / 25.6f; // 1/(sqrt(C)*sqrt(C)*TEMP)

using f32x4  = __attribute__((ext_vector_type(4))) float;
using bf16x8 = __attribute__((ext_vector_type(8))) short;
using u32x4  = __attribute__((ext_vector_type(4))) unsigned int;

// ---------------- zero stats (replaces hipMemsetAsync graph node) ----------------
__global__ __launch_bounds__(256) void init_stats(unsigned int* __restrict__ p, int n) {
    int i = blockIdx.x * 256 + threadIdx.x;
    if (i < n) p[i] = 0u;
}

// ---------------- fp32 -> bf16 (RNE) conversion, both inputs in one launch ----------------
__device__ inline unsigned short bf16_rne(float x) {
    unsigned u = __float_as_uint(x);
    unsigned r = (u + 0x7FFFu + ((u >> 16) & 1u)) >> 16;
    return (unsigned short)r;
}

__global__ __launch_bounds__(256) void cvt_bf16(const float* __restrict__ in0,
                                                const float* __restrict__ in1,
                                                unsigned short* __restrict__ out0,
                                                unsigned short* __restrict__ out1,
                                                int n8) {
    const float* in = blockIdx.y ? in1 : in0;
    unsigned short* out = blockIdx.y ? out1 : out0;
    int i = blockIdx.x * 256 + threadIdx.x;
    if (i >= n8) return;
    f32x4 a = *(const f32x4*)(in + (size_t)i * 8);
    f32x4 b = *(const f32x4*)(in + (size_t)i * 8 + 4);
    union { unsigned short us[8]; u32x4 v; } r;
#pragma unroll
    for (int j = 0; j < 4; j++) r.us[j] = bf16_rne(a[j]);
#pragma unroll
    for (int j = 0; j < 4; j++) r.us[4 + j] = bf16_rne(b[j]);
    *(u32x4*)(out + (size_t)i * 8) = r.v;
}

// ---------------- GEMM: e = exp(sim), sim = A·B^T/25.6, + exp-sum stats ----------------
// Tile 96x96, 4 waves (2x2), each wave 48x48 = 3x3 frags of 16x16x32 MFMA.
// Staging: global_load_lds dwordx4, pre-swizzled global source, linear LDS dest,
// XOR-swizzled ds_read (conflict-free; rule 21 both-sides pattern).
#define BM 96
#define BK 64

__device__ inline void gload16(const void* g, void* l) {
    __builtin_amdgcn_global_load_lds(
        (const __attribute__((address_space(1))) unsigned int*)g,
        (__attribute__((address_space(3))) unsigned int*)l, 16, 0, 0);
}

__global__ __launch_bounds__(256) void gemm_stats(
    const unsigned short* __restrict__ Abf,  // [N,L,C] bf16
    const unsigned short* __restrict__ Bbf,  // [N,S,C] bf16
    float* __restrict__ e_out,               // [N,L,S] exp(sim) (conf region of d_out)
    float* __restrict__ rowSum,              // [N,L]  sum_s exp(sim)
    float* __restrict__ colSum)              // [N,S]  sum_l exp(sim)
{
    __shared__ unsigned short As[BM * BK];
    __shared__ unsigned short Bs[BM * BK];

    const int n  = blockIdx.z;
    const int rb = blockIdx.y * BM;
    const int cb = blockIdx.x * BM;
    const int t  = threadIdx.x;
    const int lane = t & 63;
    const int wid  = t >> 6;
    const int wr = wid >> 1, wc = wid & 1;

    const unsigned short* Ag = Abf + ((size_t)n * L + rb) * C;
    const unsigned short* Bg = Bbf + ((size_t)n * S + cb) * C;

    f32x4 acc[3][3] = {};

    for (int kt = 0; kt < C; kt += BK) {
        // stage 96x64 bf16 tiles: 768 16B chunks each, 3 gload_lds per thread per tile.
        // LDS[row][c] (c = 16B-chunk 0..7) holds global chunk c^(row&7).
#pragma unroll
        for (int i = 0; i < 3; i++) {
            int idx = wid * 192 + i * 64 + lane;   // 0..767, lane-contiguous per wave-instr
            int row = idx >> 3;
            int src = ((idx & 7) ^ (row & 7)) * 8 + kt;   // pre-swizzled source col (elems)
            void* ldsA = &As[(wid * 192 + i * 64) * 8];   // wave-uniform base; +lane*16B in HW
            void* ldsB = &Bs[(wid * 192 + i * 64) * 8];
            gload16(Ag + (size_t)row * C + src, ldsA);
            gload16(Bg + (size_t)row * C + src, ldsB);
        }
        __syncthreads();

#pragma unroll
        for (int kk = 0; kk < 2; kk++) {
            bf16x8 a[3], b[3];
            const int kElem = kk * 32 + (lane >> 4) * 8;
#pragma unroll
            for (int f = 0; f < 3; f++) {
                int ra = wr * 48 + f * 16 + (lane & 15);
                a[f] = *(const bf16x8*)&As[ra * 64 + (kElem ^ ((ra & 7) << 3))];
                int rbi = wc * 48 + f * 16 + (lane & 15);
                b[f] = *(const bf16x8*)&Bs[rbi * 64 + (kElem ^ ((rbi & 7) << 3))];
            }
            // swapped operands: mfma(B-frag, A-frag) -> lane holds fixed l=lane&15,
            // 4 consecutive s in regs -> vectorized f32x4 stores in epilogue.
#pragma unroll
            for (int fi = 0; fi < 3; fi++)
#pragma unroll
                for (int fj = 0; fj < 3; fj++)
                    acc[fi][fj] = __builtin_amdgcn_mfma_f32_16x16x32_bf16(
                        b[fj], a[fi], acc[fi][fj], 0, 0, 0);
        }
        __syncthreads();
    }

    // epilogue: e = exp(sim); write f32x4; accumulate row/col exp-sums
    const int rowBase = rb + wr * 48;
    const int colBase = cb + wc * 48;
    float csum[3][4] = {};

#pragma unroll
    for (int fi = 0; fi < 3; fi++) {
        const int l = rowBase + fi * 16 + (lane & 15);
        float rsum = 0.f;
#pragma unroll
        for (int fj = 0; fj < 3; fj++) {
            const int s0 = colBase + fj * 16 + ((lane >> 4) << 2);
            f32x4 ev;
#pragma unroll
            for (int r = 0; r < 4; r++) {
                ev[r] = __expf(acc[fi][fj][r] * SIM_SCALE);
                rsum += ev[r];
                csum[fj][r] += ev[r];
            }
            *(f32x4*)&e_out[((size_t)n * L + l) * S + s0] = ev;
        }
        rsum += __shfl_xor(rsum, 16);
        rsum += __shfl_xor(rsum, 32);
        if (lane < 16)
            atomicAdd(&rowSum[(size_t)n * L + l], rsum);
    }
#pragma unroll
    for (int fj = 0; fj < 3; fj++)
#pragma unroll
        for (int r = 0; r < 4; r++) {
            float v = csum[fj][r];
            v += __shfl_xor(v, 1);
            v += __shfl_xor(v, 2);
            v += __shfl_xor(v, 4);
            v += __shfl_xor(v, 8);
            if ((lane & 15) == 0)
                atomicAdd(&colSum[(size_t)n * S + colBase + fj * 16 + ((lane >> 4) << 2) + r], v);
        }
}

// ---------------- conf = e^2/(D1[s]*D2[l]) in-place, + row/col max ----------------
__global__ __launch_bounds__(256) void conf_pass(
    float* __restrict__ conf,             // in: e=exp(sim), out: conf  [N,L,S]
    const float* __restrict__ rowSum,     // [N,L]
    const float* __restrict__ colSum,     // [N,S]
    unsigned int* __restrict__ rowMax,    // [N,L] float bits
    unsigned int* __restrict__ colMax)    // [N,S] float bits
{
    const int ROWS = 32;
    const int CBLK = 19;                  // ceil(4800/256)
    const int tilesPerN = (L / ROWS) * CBLK;
    const int wid = threadIdx.x >> 6, lane = threadIdx.x & 63;
    const int tw = blockIdx.x * 4 + wid;
    if (tw >= Nb * tilesPerN) return;
    const int n   = tw / tilesPerN;
    const int rem = tw % tilesPerN;
    const int r0  = (rem / CBLK) * ROWS;
    const int c   = (rem % CBLK) * 256 + lane * 4;
    const bool act = (c < S);

    f32x4 invD1 = {0.f, 0.f, 0.f, 0.f};
    if (act) {
        f32x4 d1 = *(const f32x4*)&colSum[(size_t)n * S + c];
#pragma unroll
        for (int j = 0; j < 4; j++) invD1[j] = 1.0f / d1[j];
    }
    f32x4 cmax = {0.f, 0.f, 0.f, 0.f};

    for (int r = r0; r < r0 + ROWS; r++) {
        float invD2 = 1.0f / rowSum[(size_t)n * L + r];
        float rmax = 0.f;
        if (act) {
            float* p = conf + ((size_t)n * L + r) * S + c;
            f32x4 sv = *(const f32x4*)p;
            f32x4 cv;
#pragma unroll
            for (int j = 0; j < 4; j++) {
                cv[j] = (sv[j] * sv[j]) * invD1[j] * invD2;   // exp(2*sim) = e*e
                cmax[j] = fmaxf(cmax[j], cv[j]);
                rmax = fmaxf(rmax, cv[j]);
            }
            *(f32x4*)p = cv;
        }
#pragma unroll
        for (int d = 1; d < 64; d <<= 1) rmax = fmaxf(rmax, __shfl_xor(rmax, d));
        if (lane == 0)
            atomicMax(&rowMax[(size_t)n * L + r], __float_as_uint(rmax));
    }
    if (act) {
#pragma unroll
        for (int j = 0; j < 4; j++)
            atomicMax(&colMax[(size_t)n * S + c + j], __float_as_uint(cmax[j]));
    }
}

// ---------------- mask ----------------
__device__ inline bool border_ok(int idx) {
    int h = idx / 80, w = idx % 80;
    return (h >= 2) & (h < 58) & (w >= 2) & (w < 78);
}

__global__ __launch_bounds__(256) void mask_pass(
    const float* __restrict__ conf,
    const unsigned int* __restrict__ rowMax,
    const unsigned int* __restrict__ colMax,
    float* __restrict__ mask)
{
    const size_t total4 = (size_t)Nb * L * S / 4;
    const size_t stride = (size_t)gridDim.x * blockDim.x;
    for (size_t i = (size_t)blockIdx.x * blockDim.x + threadIdx.x; i < total4; i += stride) {
        size_t row = i / (S / 4);          // n*L + l
        int c4 = (int)(i % (S / 4));
        int n = (int)(row / L);
        int l = (int)(row % L);
        int s0 = c4 * 4;
        f32x4 cv = *(const f32x4*)&conf[i * 4];
        unsigned rm = rowMax[row];
        u32x4 cm = *(const u32x4*)&colMax[(size_t)n * S + s0];
        bool vL = border_ok(l);
        f32x4 mv;
#pragma unroll
        for (int j = 0; j < 4; j++) {
            unsigned cb = __float_as_uint(cv[j]);
            bool m = (cv[j] > THR) && vL && border_ok(s0 + j) && (cb == rm) && (cb == cm[j]);
            mv[j] = m ? 1.0f : 0.0f;
        }
        *(f32x4*)&mask[i * 4] = mv;
    }
}

// ---------------- launch ----------------
extern "C" void kernel_launch(void* const* d_in, const int* in_sizes, int n_in,
                              void* d_out, int out_size, void* d_ws, size_t ws_size,
                              hipStream_t stream) {
    (void)in_sizes; (void)n_in; (void)out_size; (void)ws_size;
    const float* f0 = (const float*)d_in[0];
    const float* f1 = (const float*)d_in[1];

    float* conf = (float*)d_out;                       // N*L*S
    float* mask = conf + (size_t)Nb * L * S;

    unsigned short* Abf = (unsigned short*)d_ws;       // N*L*C bf16
    unsigned short* Bbf = Abf + (size_t)Nb * L * C;
    float* rowSum = (float*)(Bbf + (size_t)Nb * S * C);
    float* colSum = rowSum + (size_t)Nb * L;
    unsigned int* rowMax = (unsigned int*)(colSum + (size_t)Nb * S);
    unsigned int* colMax = rowMax + (size_t)Nb * L;

    const int nStats = 2 * (Nb * L + Nb * S);          // rowSum,colSum,rowMax,colMax contiguous
    init_stats<<<(nStats + 255) / 256, 256, 0, stream>>>((unsigned int*)rowSum, nStats);

    const int n8 = Nb * L * C / 8;
    cvt_bf16<<<dim3((n8 + 255) / 256, 2), 256, 0, stream>>>(f0, f1, Abf, Bbf, n8);

    gemm_stats<<<dim3(S / BM, L / BM, Nb), 256, 0, stream>>>(Abf, Bbf, conf, rowSum, colSum);

    const int nTiles = Nb * (L / 32) * 19;
    conf_pass<<<(nTiles + 3) / 4, 256, 0, stream>>>(conf, rowSum, colSum, rowMax, colMax);

    mask_pass<<<4096, 256, 0, stream>>>(conf, rowMax, colMax, mask);
}

// Round 3
// 164.962 us; speedup vs baseline: 1.3597x; 1.2501x over previous
//
#include <hip/hip_runtime.h>
#include <hip/hip_bf16.h>
#include <cstdint>

static constexpr int   Nb = 2;
static constexpr int   L  = 4800;
static constexpr int   S  = 4800;
static constexpr int   C  = 256;
static constexpr float THR = 0.2f;
static constexpr float SIM_SCALE = 1.0f / 25.6f;   // 1/(sqrt(C)*sqrt(C)*TEMP)
static constexpr unsigned CAND_CAP = 65536;        // hard math bound is 38400 (<=4/row)

using f32x4  = __attribute__((ext_vector_type(4))) float;
using bf16x8 = __attribute__((ext_vector_type(8))) short;
using u32x4  = __attribute__((ext_vector_type(4))) unsigned int;

// ---------------- zero stats + candidate counter ----------------
__global__ __launch_bounds__(256) void init_stats(unsigned int* __restrict__ p, int n) {
    int i = blockIdx.x * 256 + threadIdx.x;
    if (i < n) p[i] = 0u;
}

// ---------------- fp32 -> bf16 (RNE), both inputs in one launch ----------------
__device__ inline unsigned short bf16_rne(float x) {
    unsigned u = __float_as_uint(x);
    unsigned r = (u + 0x7FFFu + ((u >> 16) & 1u)) >> 16;
    return (unsigned short)r;
}

__global__ __launch_bounds__(256) void cvt_bf16(const float* __restrict__ in0,
                                                const float* __restrict__ in1,
                                                unsigned short* __restrict__ out0,
                                                unsigned short* __restrict__ out1,
                                                int n8) {
    const float* in = blockIdx.y ? in1 : in0;
    unsigned short* out = blockIdx.y ? out1 : out0;
    int i = blockIdx.x * 256 + threadIdx.x;
    if (i >= n8) return;
    f32x4 a = *(const f32x4*)(in + (size_t)i * 8);
    f32x4 b = *(const f32x4*)(in + (size_t)i * 8 + 4);
    union { unsigned short us[8]; u32x4 v; } r;
#pragma unroll
    for (int j = 0; j < 4; j++) r.us[j] = bf16_rne(a[j]);
#pragma unroll
    for (int j = 0; j < 4; j++) r.us[4 + j] = bf16_rne(b[j]);
    *(u32x4*)(out + (size_t)i * 8) = r.v;
}

__device__ inline bool border_ok(int idx) {
    int h = idx / 80, w = idx % 80;
    return (h >= 2) & (h < 58) & (w >= 2) & (w < 78);
}

// ---------------- GEMM core, two epilogue modes ----------------
// Tile 96x96, 4 waves (2x2), wave 48x48 = 3x3 frags of mfma_f32_16x16x32_bf16.
// Staging: global_load_lds dwordx4, pre-swizzled source, linear LDS dest,
// XOR-swizzled ds_read (rule-21 both-sides pattern).
// MODE 0: accumulate rowSum/colSum of exp(sim) only (no matrix write).
// MODE 1: recompute; write conf + zero mask + row/col bit-max + candidate list.
#define BM 96
#define BK 64

__device__ inline void gload16(const void* g, void* l) {
    __builtin_amdgcn_global_load_lds(
        (const __attribute__((address_space(1))) unsigned int*)g,
        (__attribute__((address_space(3))) unsigned int*)l, 16, 0, 0);
}

template <int MODE>
__global__ __launch_bounds__(256) void gemm_pass(
    const unsigned short* __restrict__ Abf,  // [N,L,C]
    const unsigned short* __restrict__ Bbf,  // [N,S,C]
    float* __restrict__ rowSum,              // [N,L]
    float* __restrict__ colSum,              // [N,S]
    float* __restrict__ conf,                // [N,L,S]      (MODE 1)
    float* __restrict__ mask,                // [N,L,S]      (MODE 1)
    unsigned* __restrict__ rowMax,           // [N,L] bits   (MODE 1)
    unsigned* __restrict__ colMax,           // [N,S] bits   (MODE 1)
    unsigned* __restrict__ cnt,              // candidate count (MODE 1)
    unsigned* __restrict__ cand)             // [CAP][2] flat,bits (MODE 1)
{
    __shared__ unsigned short As[BM * BK];
    __shared__ unsigned short Bs[BM * BK];

    const int n  = blockIdx.z;
    const int rb = blockIdx.y * BM;
    const int cb = blockIdx.x * BM;
    const int t  = threadIdx.x;
    const int lane = t & 63;
    const int wid  = t >> 6;
    const int wr = wid >> 1, wc = wid & 1;

    const unsigned short* Ag = Abf + ((size_t)n * L + rb) * C;
    const unsigned short* Bg = Bbf + ((size_t)n * S + cb) * C;

    f32x4 acc[3][3] = {};

    for (int kt = 0; kt < C; kt += BK) {
#pragma unroll
        for (int i = 0; i < 3; i++) {
            int idx = wid * 192 + i * 64 + lane;
            int row = idx >> 3;
            int src = ((idx & 7) ^ (row & 7)) * 8 + kt;
            void* ldsA = &As[(wid * 192 + i * 64) * 8];
            void* ldsB = &Bs[(wid * 192 + i * 64) * 8];
            gload16(Ag + (size_t)row * C + src, ldsA);
            gload16(Bg + (size_t)row * C + src, ldsB);
        }
        __syncthreads();

#pragma unroll
        for (int kk = 0; kk < 2; kk++) {
            bf16x8 a[3], b[3];
            const int kElem = kk * 32 + (lane >> 4) * 8;
#pragma unroll
            for (int f = 0; f < 3; f++) {
                int ra = wr * 48 + f * 16 + (lane & 15);
                a[f] = *(const bf16x8*)&As[ra * 64 + (kElem ^ ((ra & 7) << 3))];
                int rbi = wc * 48 + f * 16 + (lane & 15);
                b[f] = *(const bf16x8*)&Bs[rbi * 64 + (kElem ^ ((rbi & 7) << 3))];
            }
            // swapped operands: lane&15 -> l, (lane>>4)*4+r -> s (4 consecutive s per acc)
#pragma unroll
            for (int fi = 0; fi < 3; fi++)
#pragma unroll
                for (int fj = 0; fj < 3; fj++)
                    acc[fi][fj] = __builtin_amdgcn_mfma_f32_16x16x32_bf16(
                        b[fj], a[fi], acc[fi][fj], 0, 0, 0);
        }
        __syncthreads();
    }

    const int rowBase = rb + wr * 48;
    const int colBase = cb + wc * 48;

    if constexpr (MODE == 0) {
        // exp-sum stats only
        float csum[3][4] = {};
#pragma unroll
        for (int fi = 0; fi < 3; fi++) {
            const int l = rowBase + fi * 16 + (lane & 15);
            float rsum = 0.f;
#pragma unroll
            for (int fj = 0; fj < 3; fj++) {
#pragma unroll
                for (int r = 0; r < 4; r++) {
                    float e = __expf(acc[fi][fj][r] * SIM_SCALE);
                    rsum += e;
                    csum[fj][r] += e;
                }
            }
            rsum += __shfl_xor(rsum, 16);
            rsum += __shfl_xor(rsum, 32);
            if (lane < 16)
                atomicAdd(&rowSum[(size_t)n * L + l], rsum);
        }
#pragma unroll
        for (int fj = 0; fj < 3; fj++)
#pragma unroll
            for (int r = 0; r < 4; r++) {
                float v = csum[fj][r];
                v += __shfl_xor(v, 1);
                v += __shfl_xor(v, 2);
                v += __shfl_xor(v, 4);
                v += __shfl_xor(v, 8);
                if ((lane & 15) == 0)
                    atomicAdd(&colSum[(size_t)n * S + colBase + fj * 16 + ((lane >> 4) << 2) + r], v);
            }
    } else {
        // conf write + mask zero + maxes + candidates
        f32x4 invD1[3];
#pragma unroll
        for (int fj = 0; fj < 3; fj++) {
            const int s0 = colBase + fj * 16 + ((lane >> 4) << 2);
            f32x4 d1 = *(const f32x4*)&colSum[(size_t)n * S + s0];
#pragma unroll
            for (int j = 0; j < 4; j++) invD1[fj][j] = 1.0f / d1[j];
        }
        float cmax[3][4] = {};
        const f32x4 zero4 = {0.f, 0.f, 0.f, 0.f};

#pragma unroll
        for (int fi = 0; fi < 3; fi++) {
            const int l = rowBase + fi * 16 + (lane & 15);
            const float invD2 = 1.0f / rowSum[(size_t)n * L + l];
            const bool bl = border_ok(l);
            float rmax = 0.f;
#pragma unroll
            for (int fj = 0; fj < 3; fj++) {
                const int s0 = colBase + fj * 16 + ((lane >> 4) << 2);
                f32x4 cv;
#pragma unroll
                for (int r = 0; r < 4; r++) {
                    float e = __expf(acc[fi][fj][r] * SIM_SCALE);
                    float c = e * e * invD1[fj][r] * invD2;
                    cv[r] = c;
                    rmax = fmaxf(rmax, c);
                    cmax[fj][r] = fmaxf(cmax[fj][r], c);
                    if (c > THR) {                       // rare (<=4 per row possible)
                        int s = s0 + r;
                        if (bl && border_ok(s)) {
                            unsigned pos = atomicAdd(cnt, 1u);
                            if (pos < CAND_CAP) {
                                unsigned flat = (unsigned)(((size_t)n * L + l) * S + s);
                                cand[2 * pos]     = flat;
                                cand[2 * pos + 1] = __float_as_uint(c);
                            }
                        }
                    }
                }
                const size_t off = ((size_t)n * L + l) * S + s0;
                *(f32x4*)&conf[off] = cv;
                *(f32x4*)&mask[off] = zero4;
            }
            rmax = fmaxf(rmax, __shfl_xor(rmax, 16));
            rmax = fmaxf(rmax, __shfl_xor(rmax, 32));
            if (lane < 16)
                atomicMax(&rowMax[(size_t)n * L + l], __float_as_uint(rmax));
        }
#pragma unroll
        for (int fj = 0; fj < 3; fj++)
#pragma unroll
            for (int r = 0; r < 4; r++) {
                float v = cmax[fj][r];
                v = fmaxf(v, __shfl_xor(v, 1));
                v = fmaxf(v, __shfl_xor(v, 2));
                v = fmaxf(v, __shfl_xor(v, 4));
                v = fmaxf(v, __shfl_xor(v, 8));
                if ((lane & 15) == 0)
                    atomicMax(&colMax[(size_t)n * S + colBase + fj * 16 + ((lane >> 4) << 2) + r],
                              __float_as_uint(v));
            }
    }
}

// ---------------- scatter the mutual-NN survivors ----------------
__global__ __launch_bounds__(256) void mask_scatter(
    const unsigned* __restrict__ cnt,
    const unsigned* __restrict__ cand,
    const unsigned* __restrict__ rowMax,
    const unsigned* __restrict__ colMax,
    float* __restrict__ mask)
{
    unsigned nc = *cnt;
    if (nc > CAND_CAP) nc = CAND_CAP;
    for (unsigned i = blockIdx.x * 256 + threadIdx.x; i < nc; i += gridDim.x * 256) {
        unsigned flat = cand[2 * i];
        unsigned bits = cand[2 * i + 1];
        unsigned row = flat / S;          // n*L + l
        unsigned s   = flat % S;
        unsigned n   = row / L;
        if (bits == rowMax[row] && bits == colMax[n * S + s])
            mask[flat] = 1.0f;
    }
}

// ---------------- launch ----------------
extern "C" void kernel_launch(void* const* d_in, const int* in_sizes, int n_in,
                              void* d_out, int out_size, void* d_ws, size_t ws_size,
                              hipStream_t stream) {
    (void)in_sizes; (void)n_in; (void)out_size; (void)ws_size;
    const float* f0 = (const float*)d_in[0];
    const float* f1 = (const float*)d_in[1];

    float* conf = (float*)d_out;                       // N*L*S
    float* mask = conf + (size_t)Nb * L * S;

    unsigned short* Abf = (unsigned short*)d_ws;       // 4.92 MB
    unsigned short* Bbf = Abf + (size_t)Nb * L * C;    // 4.92 MB
    float* rowSum = (float*)(Bbf + (size_t)Nb * S * C);
    float* colSum = rowSum + (size_t)Nb * L;
    unsigned* rowMax = (unsigned*)(colSum + (size_t)Nb * S);
    unsigned* colMax = rowMax + (size_t)Nb * L;
    unsigned* cnt    = colMax + (size_t)Nb * S;
    unsigned* cand   = cnt + 2;                        // 8B-aligned, 512 KB

    const int nStats = 2 * (Nb * L + Nb * S) + 1;      // sums + maxes + counter
    init_stats<<<(nStats + 255) / 256, 256, 0, stream>>>((unsigned*)rowSum, nStats);

    const int n8 = Nb * L * C / 8;
    cvt_bf16<<<dim3((n8 + 255) / 256, 2), 256, 0, stream>>>(f0, f1, Abf, Bbf, n8);

    dim3 grid(S / BM, L / BM, Nb);
    gemm_pass<0><<<grid, 256, 0, stream>>>(Abf, Bbf, rowSum, colSum,
                                           nullptr, nullptr, nullptr, nullptr, nullptr, nullptr);
    gemm_pass<1><<<grid, 256, 0, stream>>>(Abf, Bbf, rowSum, colSum,
                                           conf, mask, rowMax, colMax, cnt, cand);

    mask_scatter<<<32, 256, 0, stream>>>(cnt, cand, rowMax, colMax, mask);
}